// Round 1
// baseline (894.285 us; speedup 1.0000x reference)
//
#include <hip/hip_runtime.h>
#include <stdint.h>

typedef __attribute__((ext_vector_type(8))) short short8;
typedef __attribute__((ext_vector_type(4))) float f32x4;
typedef __attribute__((ext_vector_type(4))) unsigned short us4;

__device__ __forceinline__ unsigned short f2bf(float f) {
  union { float f; unsigned int i; } v; v.f = f;
  unsigned int r = (v.i + 0x7FFFu + ((v.i >> 16) & 1u)) >> 16;
  return (unsigned short)r;
}
__device__ __forceinline__ float hswish(float x) {
  float t = fminf(fmaxf(x + 3.f, 0.f), 6.f);
  return x * t * (1.f / 6.f);
}

// ---------------------------------------------------------------------------
// Prep: cwLT_s[o][m] (bf16), m = j*128 + i  <-  cw_s[o][i][j]  (fp32)
// ---------------------------------------------------------------------------
__global__ void prep_kernel(const float* __restrict__ cw0,
                            const float* __restrict__ cw1,
                            const float* __restrict__ cw2,
                            unsigned short* __restrict__ cwLT0,
                            unsigned short* __restrict__ cwLT1,
                            unsigned short* __restrict__ cwLT2) {
  int idx = blockIdx.x * 256 + threadIdx.x;
  if (idx < 16384) {
    // k=1: m = i, identity layout
    cwLT0[idx] = f2bf(cw0[idx]);
  } else if (idx < 16384 + 32768) {
    int t = idx - 16384;
    int o = t >> 8, m = t & 255;
    int j = m >> 7, i = m & 127;
    cwLT1[o * 256 + m] = f2bf(cw1[(o * 128 + i) * 2 + j]);
  } else if (idx < 114688) {
    int t = idx - 49152;
    int o = t >> 9, m = t & 511;
    int j = m >> 7, i = m & 127;
    cwLT2[o * 512 + m] = f2bf(cw2[(o * 128 + i) * 4 + j]);
  }
}

// ---------------------------------------------------------------------------
// Stage 1: per-(sample, scale) block. conv -> LN -> TM1 -> TM2 -> fc dot.
// ---------------------------------------------------------------------------
template <int S>
__launch_bounds__(256, 2)
__global__ void s1_kernel(const float* __restrict__ x,
                          const float* __restrict__ cb,
                          const float* __restrict__ lg,
                          const float* __restrict__ lb,
                          const float* __restrict__ L1,
                          const float* __restrict__ L2,
                          const float* __restrict__ fc_w,
                          const float* __restrict__ fc_b,
                          const unsigned short* __restrict__ cwLT,
                          float* __restrict__ h_out) {
  constexpr int K   = 128 << S;        // conv reduction dim
  constexpr int TK  = 128 >> S;        // time steps at this scale
  constexpr int OFF = (S == 0) ? 0 : (S == 1 ? 128 : 192);
  constexpr int nT  = (S == 0) ? 2 : 1;  // t-tiles per wave
  constexpr int nO  = (S == 2) ? 4 : 8;  // o-tiles per wave
  constexpr int CW  = (TK >= 64) ? 64 : TK;  // TM k-chunk width
  constexpr int NCC = K / 64;          // conv chunks
  constexpr int NTC = TK / CW;         // TM chunks
  constexpr int HTP = TK + 8;          // HT row stride (bf16 elems)
  constexpr int LP  = CW + 8;          // L-chunk row stride
  constexpr int R1E = (HTP > 72 ? HTP : 72) * 128;

  extern __shared__ char smem[];
  unsigned short* R0 = (unsigned short*)smem;                    // A-chunk / L-chunk
  unsigned short* R1 = (unsigned short*)(smem + TK * 72 * 2);    // B-chunk, then HT/UT
  float* scratch = (float*)(smem + TK * 72 * 2 + R1E * 2);
  // scratch: [0..127]=fcw  [128..255]=part  [256..263]=red  [264]=mu [265]=rsig

  const int tid  = threadIdx.x;
  const int wave = tid >> 6;
  const int lane = tid & 63;
  const int quad = lane >> 4;
  const int l16  = lane & 15;
  const int n    = blockIdx.x;
  const float* xn = x + (size_t)n * (128 * 128);

  const int Tbase = (S == 0) ? wave * 2 : ((S == 1) ? wave : (wave & 1));
  const int Obase = (S == 2) ? ((wave >> 1) * 4) : 0;

  if (tid < 128) scratch[tid] = fc_w[tid];
  if (tid < TK) scratch[128 + tid] = 0.f;

  f32x4 acc[nT][nO];
#pragma unroll
  for (int tt = 0; tt < nT; ++tt)
#pragma unroll
    for (int oo = 0; oo < nO; ++oo)
      acc[tt][oo] = (f32x4){0.f, 0.f, 0.f, 0.f};

  // ---------------- conv: XT = Xr @ cwLT^T ----------------
  for (int c = 0; c < NCC; ++c) {
    for (int i = tid; i < TK * 16; i += 256) {   // stage A (fp32 -> bf16)
      int t = i >> 4, c4 = (i & 15) * 4;
      const float4 v = *(const float4*)(xn + t * K + c * 64 + c4);
      us4 p; p[0] = f2bf(v.x); p[1] = f2bf(v.y); p[2] = f2bf(v.z); p[3] = f2bf(v.w);
      *(us4*)&R0[t * 72 + c4] = p;
    }
    for (int i = tid; i < 128 * 16; i += 256) {  // stage B (bf16 copy)
      int o = i >> 4, c4 = (i & 15) * 4;
      *(us4*)&R1[o * 72 + c4] = *(const us4*)&cwLT[o * K + c * 64 + c4];
    }
    __syncthreads();
#pragma unroll
    for (int ks = 0; ks < 2; ++ks) {
      short8 a[nT];
#pragma unroll
      for (int tt = 0; tt < nT; ++tt)
        a[tt] = *(const short8*)&R0[((Tbase + tt) * 16 + l16) * 72 + ks * 32 + quad * 8];
#pragma unroll
      for (int oo = 0; oo < nO; ++oo) {
        short8 b = *(const short8*)&R1[((Obase + oo) * 16 + l16) * 72 + ks * 32 + quad * 8];
#pragma unroll
        for (int tt = 0; tt < nT; ++tt)
          acc[tt][oo] = __builtin_amdgcn_mfma_f32_16x16x32_bf16(a[tt], b, acc[tt][oo], 0, 0, 0);
      }
    }
    __syncthreads();
  }

  // ---------------- +cb, LayerNorm stats over (TK,128) ----------------
  float sum = 0.f, ss = 0.f;
#pragma unroll
  for (int oo = 0; oo < nO; ++oo) {
    float cbv = cb[(Obase + oo) * 16 + l16];
#pragma unroll
    for (int tt = 0; tt < nT; ++tt)
#pragma unroll
      for (int r = 0; r < 4; ++r) {
        float v = acc[tt][oo][r] + cbv;
        acc[tt][oo][r] = v;
        sum += v; ss += v * v;
      }
  }
#pragma unroll
  for (int m = 32; m >= 1; m >>= 1) {
    sum += __shfl_xor(sum, m);
    ss  += __shfl_xor(ss, m);
  }
  if (lane == 0) { scratch[256 + wave * 2] = sum; scratch[257 + wave * 2] = ss; }
  __syncthreads();
  if (tid == 0) {
    float Sm = 0.f, Ssq = 0.f;
    for (int w = 0; w < 4; ++w) { Sm += scratch[256 + w * 2]; Ssq += scratch[257 + w * 2]; }
    float mu = Sm / (float)(TK * 128);
    float var = Ssq / (float)(TK * 128) - mu * mu;
    scratch[264] = mu;
    scratch[265] = rsqrtf(var + 1e-5f);
  }
  __syncthreads();
  const float mu = scratch[264], rsig = scratch[265];

  // ---------------- write HT[f][t] = bf16(h) into R1 ----------------
  unsigned short* HT = R1;
#pragma unroll
  for (int tt = 0; tt < nT; ++tt)
#pragma unroll
    for (int oo = 0; oo < nO; ++oo) {
      int o = (Obase + oo) * 16 + l16;
#pragma unroll
      for (int r = 0; r < 4; ++r) {
        int t = (Tbase + tt) * 16 + quad * 4 + r;
        float hv = (acc[tt][oo][r] - mu) * rsig * lg[t * 128 + o] + lb[t * 128 + o];
        HT[o * HTP + t] = f2bf(hv);
      }
    }

  // ---------------- TM1: U = hswish(tril(L1) @ H) ----------------
  f32x4 uacc[nT][nO];
#pragma unroll
  for (int tt = 0; tt < nT; ++tt)
#pragma unroll
    for (int oo = 0; oo < nO; ++oo)
      uacc[tt][oo] = (f32x4){0.f, 0.f, 0.f, 0.f};

  for (int c = 0; c < NTC; ++c) {
    for (int i = tid; i < TK * (CW / 4); i += 256) {
      int t = i / (CW / 4), s4 = (i % (CW / 4)) * 4;
      int sg = c * CW + s4;
      const float4 v = *(const float4*)(L1 + t * TK + sg);
      us4 p;
      p[0] = (sg     <= t) ? f2bf(v.x) : (unsigned short)0;
      p[1] = (sg + 1 <= t) ? f2bf(v.y) : (unsigned short)0;
      p[2] = (sg + 2 <= t) ? f2bf(v.z) : (unsigned short)0;
      p[3] = (sg + 3 <= t) ? f2bf(v.w) : (unsigned short)0;
      *(us4*)&R0[t * LP + s4] = p;
    }
    __syncthreads();
#pragma unroll
    for (int ks = 0; ks < CW / 32; ++ks) {
      int k0 = c * CW + ks * 32;
      if (k0 <= (Tbase + nT - 1) * 16 + 15) {
        short8 a[nT];
#pragma unroll
        for (int tt = 0; tt < nT; ++tt)
          a[tt] = *(const short8*)&R0[((Tbase + tt) * 16 + l16) * LP + ks * 32 + quad * 8];
#pragma unroll
        for (int oo = 0; oo < nO; ++oo) {
          short8 b = *(const short8*)&HT[((Obase + oo) * 16 + l16) * HTP + k0 + quad * 8];
#pragma unroll
          for (int tt = 0; tt < nT; ++tt)
            if (k0 <= (Tbase + tt) * 16 + 15)
              uacc[tt][oo] = __builtin_amdgcn_mfma_f32_16x16x32_bf16(a[tt], b, uacc[tt][oo], 0, 0, 0);
        }
      }
      __syncthreads();
    }
  }

  // hswish, then overwrite HT with UT (all HT reads completed at last sync)
#pragma unroll
  for (int tt = 0; tt < nT; ++tt)
#pragma unroll
    for (int oo = 0; oo < nO; ++oo) {
      int f = (Obase + oo) * 16 + l16;
#pragma unroll
      for (int r = 0; r < 4; ++r) {
        int t = (Tbase + tt) * 16 + quad * 4 + r;
        float uv = hswish(uacc[tt][oo][r]);
        HT[f * HTP + t] = f2bf(uv);
      }
    }

  // ---------------- TM2: acc += tril(L2) @ U  (gives xt + v) ----------------
  for (int c = 0; c < NTC; ++c) {
    for (int i = tid; i < TK * (CW / 4); i += 256) {
      int t = i / (CW / 4), s4 = (i % (CW / 4)) * 4;
      int sg = c * CW + s4;
      const float4 v = *(const float4*)(L2 + t * TK + sg);
      us4 p;
      p[0] = (sg     <= t) ? f2bf(v.x) : (unsigned short)0;
      p[1] = (sg + 1 <= t) ? f2bf(v.y) : (unsigned short)0;
      p[2] = (sg + 2 <= t) ? f2bf(v.z) : (unsigned short)0;
      p[3] = (sg + 3 <= t) ? f2bf(v.w) : (unsigned short)0;
      *(us4*)&R0[t * LP + s4] = p;
    }
    __syncthreads();
#pragma unroll
    for (int ks = 0; ks < CW / 32; ++ks) {
      int k0 = c * CW + ks * 32;
      if (k0 <= (Tbase + nT - 1) * 16 + 15) {
        short8 a[nT];
#pragma unroll
        for (int tt = 0; tt < nT; ++tt)
          a[tt] = *(const short8*)&R0[((Tbase + tt) * 16 + l16) * LP + ks * 32 + quad * 8];
#pragma unroll
        for (int oo = 0; oo < nO; ++oo) {
          short8 b = *(const short8*)&HT[((Obase + oo) * 16 + l16) * HTP + k0 + quad * 8];
#pragma unroll
          for (int tt = 0; tt < nT; ++tt)
            if (k0 <= (Tbase + tt) * 16 + 15)
              acc[tt][oo] = __builtin_amdgcn_mfma_f32_16x16x32_bf16(a[tt], b, acc[tt][oo], 0, 0, 0);
        }
      }
      __syncthreads();
    }
  }

  // ---------------- fc: part[t] = sum_o xtf[t][o] * fc_w[o] ----------------
  float* part = scratch + 128;
#pragma unroll
  for (int tt = 0; tt < nT; ++tt)
#pragma unroll
    for (int r = 0; r < 4; ++r) {
      float v = 0.f;
#pragma unroll
      for (int oo = 0; oo < nO; ++oo)
        v += acc[tt][oo][r] * scratch[(Obase + oo) * 16 + l16];
      v += __shfl_xor(v, 1); v += __shfl_xor(v, 2);
      v += __shfl_xor(v, 4); v += __shfl_xor(v, 8);
      if (l16 == 0) atomicAdd(&part[(Tbase + tt) * 16 + quad * 4 + r], v);
    }
  __syncthreads();
  if (tid < TK) h_out[(size_t)n * 224 + OFF + tid] = part[tid] + fc_b[0];
}

// ---------------------------------------------------------------------------
// Stage 2
// ---------------------------------------------------------------------------
__global__ void stats_kernel(const float* __restrict__ h, float* __restrict__ stats) {
  int base = blockIdx.x * 4096;
  float s = 0.f, ss = 0.f;
  for (int j = 0; j < 16; ++j) {
    float v = h[base + j * 256 + threadIdx.x];
    s += v; ss += v * v;
  }
  int lane = threadIdx.x & 63, wave = threadIdx.x >> 6;
#pragma unroll
  for (int m = 32; m >= 1; m >>= 1) { s += __shfl_xor(s, m); ss += __shfl_xor(ss, m); }
  __shared__ float red[8];
  if (lane == 0) { red[wave * 2] = s; red[wave * 2 + 1] = ss; }
  __syncthreads();
  if (threadIdx.x == 0) {
    atomicAdd(&stats[0], red[0] + red[2] + red[4] + red[6]);
    atomicAdd(&stats[1], red[1] + red[3] + red[5] + red[7]);
  }
}

__global__ void mix1_kernel(const float* __restrict__ h,
                            const float* __restrict__ sm_lg,
                            const float* __restrict__ sm_lb,
                            const float* __restrict__ M1,
                            const float* __restrict__ stats,
                            float* __restrict__ A) {
  const int m = blockIdx.x;            // 0..223
  const int seg = blockIdx.y;          // 0..3
  const int r = threadIdx.x & 63;
  const int ch = threadIdx.x >> 6;
  const float inv = 1.f / 917504.f;
  float mu = stats[0] * inv;
  float var = stats[1] * inv - mu * mu;
  float rsig = rsqrtf(var + 1e-5f);
  float acc = 0.f;
  int n0 = seg * 1024 + ch * 256;
  for (int i = 0; i < 256; ++i) {
    int n = n0 + i;
    float hn = (h[n * 224 + m] - mu) * rsig * sm_lg[n * 224 + m] + sm_lb[n * 224 + m];
    acc += M1[r * 4096 + n] * hn;
  }
  __shared__ float red[256];
  red[threadIdx.x] = acc;
  __syncthreads();
  if (threadIdx.x < 64)
    atomicAdd(&A[threadIdx.x * 224 + m],
              red[threadIdx.x] + red[64 + threadIdx.x] + red[128 + threadIdx.x] + red[192 + threadIdx.x]);
}

__global__ void mix2_kernel(const float* __restrict__ A,
                            const float* __restrict__ sm_fc_w,
                            float* __restrict__ cvec) {
  int r = threadIdx.x & 63, ch = threadIdx.x >> 6;
  float acc = 0.f;
  for (int j = ch; j < 224; j += 4)
    acc += hswish(A[r * 224 + j]) * sm_fc_w[224 + j];
  __shared__ float red[256];
  red[threadIdx.x] = acc;
  __syncthreads();
  if (threadIdx.x < 64)
    cvec[threadIdx.x] = red[threadIdx.x] + red[64 + threadIdx.x] + red[128 + threadIdx.x] + red[192 + threadIdx.x];
}

__global__ void out_kernel(const float* __restrict__ h,
                           const float* __restrict__ M2,
                           const float* __restrict__ cvec,
                           const float* __restrict__ sm_fc_w,
                           const float* __restrict__ sm_fc_b,
                           float* __restrict__ out) {
  int wave = threadIdx.x >> 6, lane = threadIdx.x & 63;
  int n = blockIdx.x * 4 + wave;
  float acc = M2[n * 64 + lane] * cvec[lane];
  for (int j = lane; j < 224; j += 64)
    acc += h[n * 224 + j] * (sm_fc_w[j] + sm_fc_w[224 + j]);
#pragma unroll
  for (int m = 32; m >= 1; m >>= 1) acc += __shfl_xor(acc, m);
  if (lane == 0) out[n] = acc + sm_fc_b[0];
}

// ---------------------------------------------------------------------------
extern "C" void kernel_launch(void* const* d_in, const int* in_sizes, int n_in,
                              void* d_out, int out_size, void* d_ws, size_t ws_size,
                              hipStream_t stream) {
  const float* x      = (const float*)d_in[0];
  const float* cw0    = (const float*)d_in[1];
  const float* cb0    = (const float*)d_in[2];
  const float* lg0    = (const float*)d_in[3];
  const float* lb0    = (const float*)d_in[4];
  const float* L1_0   = (const float*)d_in[5];
  const float* L2_0   = (const float*)d_in[6];
  const float* cw1    = (const float*)d_in[7];
  const float* cb1    = (const float*)d_in[8];
  const float* lg1    = (const float*)d_in[9];
  const float* lb1    = (const float*)d_in[10];
  const float* L1_1   = (const float*)d_in[11];
  const float* L2_1   = (const float*)d_in[12];
  const float* cw2    = (const float*)d_in[13];
  const float* cb2    = (const float*)d_in[14];
  const float* lg2    = (const float*)d_in[15];
  const float* lb2    = (const float*)d_in[16];
  const float* L1_2   = (const float*)d_in[17];
  const float* L2_2   = (const float*)d_in[18];
  const float* fc_w   = (const float*)d_in[19];
  const float* fc_b   = (const float*)d_in[20];
  const float* sm_lg  = (const float*)d_in[21];
  const float* sm_lb  = (const float*)d_in[22];
  const float* M1     = (const float*)d_in[23];
  const float* M2     = (const float*)d_in[24];
  const float* sm_fc_w = (const float*)d_in[25];
  const float* sm_fc_b = (const float*)d_in[26];

  char* ws = (char*)d_ws;
  unsigned short* cwLT0 = (unsigned short*)(ws);            // 32768 B
  unsigned short* cwLT1 = (unsigned short*)(ws + 32768);    // 65536 B
  unsigned short* cwLT2 = (unsigned short*)(ws + 98304);    // 131072 B
  float* h     = (float*)(ws + 229376);                     // 3670016 B
  float* stats = (float*)(ws + 3899392);                    // 8 B
  float* A     = (float*)(ws + 3899648);                    // 57344 B
  float* cvec  = (float*)(ws + 3956992);                    // 256 B

  prep_kernel<<<448, 256, 0, stream>>>(cw0, cw1, cw2, cwLT0, cwLT1, cwLT2);

  auto smemBytes = [](int S) -> size_t {
    int TK = 128 >> S;
    int HTP = TK + 8;
    int r1 = (HTP > 72 ? HTP : 72) * 128;
    return (size_t)TK * 72 * 2 + (size_t)r1 * 2 + 266 * 4;
  };

  s1_kernel<0><<<4096, 256, smemBytes(0), stream>>>(x, cb0, lg0, lb0, L1_0, L2_0, fc_w, fc_b, cwLT0, h);
  s1_kernel<1><<<4096, 256, smemBytes(1), stream>>>(x, cb1, lg1, lb1, L1_1, L2_1, fc_w, fc_b, cwLT1, h);
  s1_kernel<2><<<4096, 256, smemBytes(2), stream>>>(x, cb2, lg2, lb2, L1_2, L2_2, fc_w, fc_b, cwLT2, h);

  // zero stats + A (one memset covers both regions)
  hipMemsetAsync(ws + 3899392, 0, 57600, stream);

  stats_kernel<<<224, 256, 0, stream>>>(h, stats);
  mix1_kernel<<<dim3(224, 4), 256, 0, stream>>>(h, sm_lg, sm_lb, M1, stats, A);
  mix2_kernel<<<1, 256, 0, stream>>>(A, sm_fc_w, cvec);
  out_kernel<<<1024, 256, 0, stream>>>(h, M2, cvec, sm_fc_w, sm_fc_b, (float*)d_out);
}